// Round 20
// baseline (135.948 us; speedup 1.0000x reference)
//
#include <hip/hip_runtime.h>

typedef unsigned short u16;
typedef unsigned int   u32;
typedef __bf16 bf16x8 __attribute__((ext_vector_type(8)));
typedef float  f32x4  __attribute__((ext_vector_type(4)));

union U16B { int4 i4; bf16x8 b8; u16 u[8]; };
union U16Q { uint2 d2; u16 u[4]; };
union PK4  { uint2 d2; __bf16 b[4]; };

static __device__ __forceinline__ u16 f2b(float f) {
  u32 x = __float_as_uint(f);
  x += 0x7FFFu + ((x >> 16) & 1u);   // RNE (inputs finite)
  return (u16)(x >> 16);
}
static __device__ __forceinline__ float b2f(u16 s) {
  return __uint_as_float(((u32)s) << 16);
}

// async global->LDS: dest must be linear (wave-uniform base + lane*16)
#define GLOAD_LDS16(g, l) \
  __builtin_amdgcn_global_load_lds((const __attribute__((address_space(1))) u32*)(g), \
                                   (__attribute__((address_space(3))) u32*)(l), 16, 0, 0)

// ---------------- prep: input fp32->bf16 convert + weight transpose ----------------
struct Prep { const float* src[3]; u16* dst[3]; const float* W[4]; u16* Wt[4]; };

__global__ __launch_bounds__(256) void prep(Prep p) {
  if (blockIdx.z < 3) {
    const float* s = p.src[blockIdx.z];
    u16*         d = p.dst[blockIdx.z];
    const size_t i = ((size_t)blockIdx.x * 256 + threadIdx.x) * 8;
    float4 f0 = *(const float4*)(s + i);
    float4 f1 = *(const float4*)(s + i + 4);
    U16B t;
    t.u[0] = f2b(f0.x); t.u[1] = f2b(f0.y); t.u[2] = f2b(f0.z); t.u[3] = f2b(f0.w);
    t.u[4] = f2b(f1.x); t.u[5] = f2b(f1.y); t.u[6] = f2b(f1.z); t.u[7] = f2b(f1.w);
    *(int4*)(d + i) = t.i4;
  } else {
    if (blockIdx.x >= 1024) return;
    const int w = blockIdx.x >> 8, tile = blockIdx.x & 255;
    const float* W  = p.W[w];
    u16*         Wt = p.Wt[w];
    __shared__ float t[64][65];
    const int bx = (tile & 15) * 64, by = (tile >> 4) * 64;
    const int tx = threadIdx.x & 63, ty = threadIdx.x >> 6;
    #pragma unroll
    for (int j = 0; j < 16; ++j) {
      int row = j * 4 + ty;
      t[row][tx] = W[(size_t)(by + row) * 1024 + bx + tx];
    }
    __syncthreads();
    #pragma unroll
    for (int j = 0; j < 16; ++j) {
      int row = j * 4 + ty;           // Wt[n][k] = W[k][n]
      Wt[(size_t)(bx + row) * 1024 + by + tx] = f2b(t[tx][row]);
    }
  }
}

// ---------------- GEMM: C = A[M][K](bf16) * Bt[N][K]^T + bias ----------------
// BM x 128 tile, BK=64, 4 waves, m97 2-barrier structure, global_load_lds
// staging. BM=64 everywhere (R15/R17 occupancy lever). Unchanged from R19.
struct GemmB { const u16* A[3]; const u16* Bt[3]; const float* bias[3]; void* C[3]; int mode[3]; int cpx; int zshift; };

template<int BM>
__global__ __launch_bounds__(256) void gemm_bt(GemmB g) {
  constexpr int K = 1024, N = 1024;
  constexpr int MF = BM / 32;
  __shared__ u16 As[BM * 64];
  __shared__ u16 Bs[128 * 64];
  const int bid = blockIdx.x;
  const int lg = (bid & 7) * g.cpx + (bid >> 3);
  const int z = lg >> g.zshift;
  const int rem = lg & ((1 << g.zshift) - 1);
  const int row0 = (rem >> 3) * BM, col0 = (rem & 7) * 128;
  const u16*   Ap   = g.A[z];
  const u16*   Bt   = g.Bt[z];
  const float* bias = g.bias[z];
  const int mode = g.mode[z];
  const int tid = threadIdx.x;
  const int wid = tid >> 6, lane = tid & 63;
  const int wr = wid >> 1, wc = wid & 1;
  const int lo = lane & 15, hi = lane >> 4;
  const int rs = tid >> 3, us = tid & 7;
  const int sw = (us ^ (rs & 7)) * 8;

  const u16* aG[MF];
  const u16* bG[4];
  #pragma unroll
  for (int c = 0; c < MF; ++c) aG[c] = Ap + (size_t)(row0 + c * 32 + rs) * K + sw;
  #pragma unroll
  for (int c = 0; c < 4; ++c)  bG[c] = Bt + (size_t)(col0 + c * 32 + rs) * K + sw;

  f32x4 acc[MF][4];
  const f32x4 z4 = {0.f, 0.f, 0.f, 0.f};
  #pragma unroll
  for (int i = 0; i < MF; ++i)
    #pragma unroll
    for (int j = 0; j < 4; ++j) acc[i][j] = z4;

  for (int kt = 0; kt < K / 64; ++kt) {
    __syncthreads();
    #pragma unroll
    for (int c = 0; c < MF; ++c) {
      GLOAD_LDS16(aG[c], &As[(c * 32 + rs) * 64 + us * 8]);
      aG[c] += 64;
    }
    #pragma unroll
    for (int c = 0; c < 4; ++c) {
      GLOAD_LDS16(bG[c], &Bs[(c * 32 + rs) * 64 + us * 8]);
      bG[c] += 64;
    }
    __syncthreads();
    #pragma unroll
    for (int ks = 0; ks < 2; ++ks) {
      bf16x8 af[MF], bfr[4];
      #pragma unroll
      for (int mf = 0; mf < MF; ++mf) {
        int r = wr * (BM / 2) + mf * 16 + lo;
        af[mf] = *(const bf16x8*)&As[r * 64 + (((ks * 4 + hi) ^ (r & 7)) << 3)];
      }
      #pragma unroll
      for (int nf = 0; nf < 4; ++nf) {
        int r = wc * 64 + nf * 16 + lo;
        bfr[nf] = *(const bf16x8*)&Bs[r * 64 + (((ks * 4 + hi) ^ (r & 7)) << 3)];
      }
      #pragma unroll
      for (int mf = 0; mf < MF; ++mf)
        #pragma unroll
        for (int nf = 0; nf < 4; ++nf)
          acc[mf][nf] = __builtin_amdgcn_mfma_f32_16x16x32_bf16(af[mf], bfr[nf], acc[mf][nf], 0, 0, 0);
    }
  }

  #pragma unroll
  for (int nf = 0; nf < 4; ++nf) {
    int col = col0 + wc * 64 + nf * 16 + lo;
    float bv = bias[col];
    #pragma unroll
    for (int mf = 0; mf < MF; ++mf) {
      int rb = row0 + wr * (BM / 2) + mf * 16 + hi * 4;
      if (mode == 2) {
        U16Q q4;
        #pragma unroll
        for (int e = 0; e < 4; ++e) q4.u[e] = f2b(acc[mf][nf][e] + bv);
        *(uint2*)&((u16*)g.C[z])[(size_t)col * 4096 + rb] = q4.d2;
      } else {
        #pragma unroll
        for (int e = 0; e < 4; ++e) {
          float v = acc[mf][nf][e] + bv;
          if (mode == 1) ((float*)g.C[z])[(size_t)(rb + e) * N + col] = v;
          else           ((u16*)g.C[z])[(size_t)(rb + e) * N + col] = f2b(v);
        }
      }
    }
  }
}

// ---------------- flash attention, KBLK=128 ----------------
// R18/R19 compute machinery (defer-max THR=8 w/ per-lane vote, PK4 pack,
// l-via-MFMA, dbuf gload_lds, ONE barrier/iter) with KBLK 64 -> 128:
// 16 sync points instead of 32 (halves per-iter fixed costs: vote tail,
// branch, drain+barrier). LDS 80KB -> 2 blocks/CU (occupancy 4->2 blocks
// measured ~neutral in R9/R10). Tiles: Ks[128 kk][64 d] (8 16B-units/row),
// Vts[64 d][128 kk] (16 units/row), Ps[64 q][128 kk] per-wave rows.
__global__ __launch_bounds__(256) void attn_fwd(const u16* __restrict__ Q,
                                                const u16* __restrict__ Kp,
                                                const u16* __restrict__ VpT,
                                                u16* __restrict__ O) {
  __shared__ u16 Ks[2][128 * 64];   // 32KB
  __shared__ u16 Vts[2][64 * 128];  // 32KB
  __shared__ u16 Ps[64 * 128];      // 16KB
  const int tid = threadIdx.x;
  const int bid = blockIdx.x;       // XCD decode: xcd=bid&7 owns 4 (h,b) pairs
  const int t = bid >> 3;
  const int hb = (bid & 7) * 4 + (t >> 5);
  const int qb = t & 31;
  const int h = hb & 15, b = hb >> 4;
  const int wid = tid >> 6, lane = tid & 63;
  const int lo = lane & 15, hi = lane >> 4;
  const int rs = tid >> 3, us = tid & 7;
  const int rv = tid >> 4, uv = tid & 15;     // V staging: row d group, 16B unit
  const int hoff = h * 64;
  const size_t rowQ0 = (size_t)b * 2048 + (size_t)qb * 64;
  const float QSCALE = 0.125f * 1.4426950408889634f;

  bf16x8 vones;
  {
    U16B t1;
    #pragma unroll
    for (int j = 0; j < 8; ++j) t1.u[j] = 0x3F80u;   // bf16 1.0
    vones = t1.b8;
  }

  // Q fragments: lane holds Q[q = wid*16+lo][d = ks*32 + hi*8 .. +8]
  bf16x8 qf[2];
  #pragma unroll
  for (int ks = 0; ks < 2; ++ks) {
    size_t r = rowQ0 + wid * 16 + lo;
    U16B in; in.i4 = *(const int4*)&Q[r * 1024 + hoff + ks * 32 + hi * 8];
    U16B o;
    #pragma unroll
    for (int j = 0; j < 8; ++j) o.u[j] = f2b(b2f(in.u[j]) * QSCALE);
    qf[ks] = o.b8;
  }

  f32x4 oacc[4];
  f32x4 lacc;                       // l in C/D layout: lacc[e] = l[q=hi*4+e]
  const f32x4 z4 = {0.f, 0.f, 0.f, 0.f};
  #pragma unroll
  for (int df = 0; df < 4; ++df) oacc[df] = z4;
  lacc = z4;
  float m_r = -1e30f;

  // staging pointers.
  // K: 4 chunks, row kk = c*32 + rs (rs&7 == kk&7), dest linear lane*16B.
  // V: 4 chunks, row d = c*16 + rv, unit uv, source col pre-swizzled uv^(d&7).
  const u16* kG[4];
  const u16* vG[4];
  #pragma unroll
  for (int c = 0; c < 4; ++c) {
    kG[c] = Kp + ((size_t)b * 2048 + c * 32 + rs) * 1024 + hoff + ((us ^ (rs & 7)) << 3);
    int d = c * 16 + rv;
    vG[c] = VpT + (size_t)(hoff + d) * 4096 + (size_t)b * 2048 + ((uv ^ (d & 7)) << 3);
  }

  // prologue: stage tile 0 into buffer 0
  #pragma unroll
  for (int c = 0; c < 4; ++c) {
    GLOAD_LDS16(kG[c], &Ks[0][(c * 32 + rs) * 64 + us * 8]);
    GLOAD_LDS16(vG[c], &Vts[0][(c * 16 + rv) * 128 + uv * 8]);
    kG[c] += 128 * 1024; vG[c] += 128;
  }

  for (int kb = 0; kb < 16; ++kb) {
    const int cur = kb & 1;
    __syncthreads();   // vmcnt drained: buf[cur] ready; buf[cur^1] readers done
    if (kb < 15) {
      const int nxt = cur ^ 1;
      #pragma unroll
      for (int c = 0; c < 4; ++c) {
        GLOAD_LDS16(kG[c], &Ks[nxt][(c * 32 + rs) * 64 + us * 8]);
        GLOAD_LDS16(vG[c], &Vts[nxt][(c * 16 + rv) * 128 + uv * 8]);
        kG[c] += 128 * 1024; vG[c] += 128;
      }
    }

    // S^T = K Q^T : frag nf covers kk = nf*16 + hi*4 + e (nf=0..7), q = wid*16+lo
    f32x4 sfr[8];
    #pragma unroll
    for (int nf = 0; nf < 8; ++nf) sfr[nf] = z4;
    #pragma unroll
    for (int ks = 0; ks < 2; ++ks) {
      #pragma unroll
      for (int nf = 0; nf < 8; ++nf) {
        int kk = nf * 16 + lo;
        bf16x8 kf = *(const bf16x8*)&Ks[cur][kk * 64 + (((ks * 4 + hi) ^ (kk & 7)) << 3)];
        sfr[nf] = __builtin_amdgcn_mfma_f32_16x16x32_bf16(kf, qf[ks], sfr[nf], 0, 0, 0);
      }
    }

    // defer-max vote on per-lane partial max (no shfl fast path)
    float pm = fmaxf(sfr[0][0], sfr[0][1]);
    #pragma unroll
    for (int nf = 0; nf < 8; ++nf)
      #pragma unroll
      for (int e = 0; e < 4; ++e)
        if (!(nf == 0 && e < 2)) pm = fmaxf(pm, sfr[nf][e]);
    if (!__all(pm <= m_r + 8.0f)) {
      pm = fmaxf(pm, __shfl_xor(pm, 16));
      pm = fmaxf(pm, __shfl_xor(pm, 32));
      float mn = fmaxf(m_r, pm);
      float cc = __builtin_amdgcn_exp2f(m_r - mn);
      m_r = mn;
      float cce[4];
      #pragma unroll
      for (int e = 0; e < 4; ++e) cce[e] = __shfl(cc, hi * 4 + e);
      #pragma unroll
      for (int df = 0; df < 4; ++df)
        #pragma unroll
        for (int e = 0; e < 4; ++e) oacc[df][e] *= cce[e];
      #pragma unroll
      for (int e = 0; e < 4; ++e) lacc[e] *= cce[e];
    }
    // P pack: value kk = nf*16+hi*4+e -> unit 2nf+(hi>>1), sub-offset (hi&1)*4
    #pragma unroll
    for (int nf = 0; nf < 8; ++nf) {
      PK4 pk;
      #pragma unroll
      for (int e = 0; e < 4; ++e)
        pk.b[e] = (__bf16)__builtin_amdgcn_exp2f(sfr[nf][e] - m_r);
      int q = wid * 16 + lo;
      int unit = 2 * nf + (hi >> 1);
      *(uint2*)&Ps[q * 128 + ((unit ^ (q & 7)) << 3) + (hi & 1) * 4] = pk.d2;
    }

    // O += P V ; l += P @ ones  (Ps rows per-wave exclusive)
    #pragma unroll
    for (int ksp = 0; ksp < 4; ++ksp) {
      int q = wid * 16 + lo;
      bf16x8 pa = *(const bf16x8*)&Ps[q * 128 + (((ksp * 4 + hi) ^ (q & 7)) << 3)];
      bf16x8 vb[4];
      #pragma unroll
      for (int df = 0; df < 4; ++df) {
        int d = df * 16 + lo;
        vb[df] = *(const bf16x8*)&Vts[cur][d * 128 + (((ksp * 4 + hi) ^ (d & 7)) << 3)];
      }
      #pragma unroll
      for (int df = 0; df < 4; ++df)
        oacc[df] = __builtin_amdgcn_mfma_f32_16x16x32_bf16(pa, vb[df], oacc[df], 0, 0, 0);
      lacc = __builtin_amdgcn_mfma_f32_16x16x32_bf16(pa, vones, lacc, 0, 0, 0);
    }
  }

  // epilogue: lacc[e] = l[q=hi*4+e] already in output layout
  float inve[4];
  #pragma unroll
  for (int e = 0; e < 4; ++e) inve[e] = __builtin_amdgcn_rcpf(lacc[e]);
  #pragma unroll
  for (int df = 0; df < 4; ++df)
    #pragma unroll
    for (int e = 0; e < 4; ++e) {
      size_t row = rowQ0 + wid * 16 + hi * 4 + e;
      O[row * 1024 + hoff + df * 16 + lo] = f2b(oacc[df][e] * inve[e]);
    }
}

// ---------------- launch ----------------
extern "C" void kernel_launch(void* const* d_in, const int* in_sizes, int n_in,
                              void* d_out, int out_size, void* d_ws, size_t ws_size,
                              hipStream_t stream) {
  (void)in_sizes; (void)n_in; (void)out_size;
  const size_t MB = 1024 * 1024;
  if (ws_size < 40 * MB) return;
  char* ws = (char*)d_ws;
  u16* Wqt = (u16*)(ws + 0 * MB);
  u16* Wkt = (u16*)(ws + 2 * MB);
  u16* Wvt = (u16*)(ws + 4 * MB);
  u16* Wot = (u16*)(ws + 6 * MB);
  u16* Vb  = (u16*)(ws + 8 * MB);    // bf16 value-input; later reused as Op
  u16* Qp  = (u16*)(ws + 16 * MB);
  u16* Kp  = (u16*)(ws + 24 * MB);
  u16* VpT = (u16*)(ws + 32 * MB);   // V^T [1024][4096]
  u16* Op  = (u16*)(ws + 8 * MB);    // reuse Vb space (dead after QKV GEMM)
  u16* Qb = (u16*)d_out;
  u16* Kb = (u16*)d_out + (size_t)4 * MB;

  Prep pp;
  pp.src[0] = (const float*)d_in[0]; pp.dst[0] = Qb;
  pp.src[1] = (const float*)d_in[1]; pp.dst[1] = Kb;
  pp.src[2] = (const float*)d_in[2]; pp.dst[2] = Vb;
  pp.W[0] = (const float*)d_in[3]; pp.Wt[0] = Wqt;
  pp.W[1] = (const float*)d_in[5]; pp.Wt[1] = Wkt;
  pp.W[2] = (const float*)d_in[7]; pp.Wt[2] = Wvt;
  pp.W[3] = (const float*)d_in[9]; pp.Wt[3] = Wot;
  hipLaunchKernelGGL(prep, dim3(2048, 1, 4), dim3(256), 0, stream, pp);

  GemmB gp;
  gp.A[0] = Qb; gp.Bt[0] = Wqt; gp.bias[0] = (const float*)d_in[4]; gp.C[0] = Qp;  gp.mode[0] = 0;
  gp.A[1] = Kb; gp.Bt[1] = Wkt; gp.bias[1] = (const float*)d_in[6]; gp.C[1] = Kp;  gp.mode[1] = 0;
  gp.A[2] = Vb; gp.Bt[2] = Wvt; gp.bias[2] = (const float*)d_in[8]; gp.C[2] = VpT; gp.mode[2] = 2;
  gp.cpx = 192; gp.zshift = 9;
  hipLaunchKernelGGL((gemm_bt<64>), dim3(1536), dim3(256), 0, stream, gp);

  hipLaunchKernelGGL(attn_fwd, dim3(1024), dim3(256), 0, stream, Qp, Kp, VpT, Op);

  GemmB gf;
  gf.A[0] = Op; gf.Bt[0] = Wot; gf.bias[0] = (const float*)d_in[10]; gf.C[0] = (void*)d_out; gf.mode[0] = 1;
  gf.A[1] = nullptr; gf.A[2] = nullptr; gf.Bt[1] = nullptr; gf.Bt[2] = nullptr;
  gf.bias[1] = nullptr; gf.bias[2] = nullptr; gf.C[1] = nullptr; gf.C[2] = nullptr;
  gf.mode[1] = 0; gf.mode[2] = 0;
  gf.cpx = 64; gf.zshift = 9;
  hipLaunchKernelGGL((gemm_bt<64>), dim3(512), dim3(256), 0, stream, gf);
}

// Round 21
// 128.653 us; speedup vs baseline: 1.0567x; 1.0567x over previous
//
#include <hip/hip_runtime.h>

typedef unsigned short u16;
typedef unsigned int   u32;
typedef __bf16 bf16x8 __attribute__((ext_vector_type(8)));
typedef float  f32x4  __attribute__((ext_vector_type(4)));

union U16B { int4 i4; bf16x8 b8; u16 u[8]; };
union U16Q { uint2 d2; u16 u[4]; };
union PK4  { uint2 d2; __bf16 b[4]; };

static __device__ __forceinline__ u16 f2b(float f) {
  u32 x = __float_as_uint(f);
  x += 0x7FFFu + ((x >> 16) & 1u);   // RNE (inputs finite)
  return (u16)(x >> 16);
}
static __device__ __forceinline__ float b2f(u16 s) {
  return __uint_as_float(((u32)s) << 16);
}

// async global->LDS: dest must be linear (wave-uniform base + lane*16)
#define GLOAD_LDS16(g, l) \
  __builtin_amdgcn_global_load_lds((const __attribute__((address_space(1))) u32*)(g), \
                                   (__attribute__((address_space(3))) u32*)(l), 16, 0, 0)

// ---------------- prep: input fp32->bf16 convert + weight transpose ----------------
// z = 0..2 : convert query/key/value (2048 x-blocks each)
// z = 3    : transpose+convert all 4 weight matrices (x = w*256 + tile; x>=1024 idle)
struct Prep { const float* src[3]; u16* dst[3]; const float* W[4]; u16* Wt[4]; };

__global__ __launch_bounds__(256) void prep(Prep p) {
  if (blockIdx.z < 3) {
    const float* s = p.src[blockIdx.z];
    u16*         d = p.dst[blockIdx.z];
    const size_t i = ((size_t)blockIdx.x * 256 + threadIdx.x) * 8;
    float4 f0 = *(const float4*)(s + i);
    float4 f1 = *(const float4*)(s + i + 4);
    U16B t;
    t.u[0] = f2b(f0.x); t.u[1] = f2b(f0.y); t.u[2] = f2b(f0.z); t.u[3] = f2b(f0.w);
    t.u[4] = f2b(f1.x); t.u[5] = f2b(f1.y); t.u[6] = f2b(f1.z); t.u[7] = f2b(f1.w);
    *(int4*)(d + i) = t.i4;
  } else {
    if (blockIdx.x >= 1024) return;
    const int w = blockIdx.x >> 8, tile = blockIdx.x & 255;
    const float* W  = p.W[w];
    u16*         Wt = p.Wt[w];
    __shared__ float t[64][65];
    const int bx = (tile & 15) * 64, by = (tile >> 4) * 64;
    const int tx = threadIdx.x & 63, ty = threadIdx.x >> 6;
    #pragma unroll
    for (int j = 0; j < 16; ++j) {
      int row = j * 4 + ty;
      t[row][tx] = W[(size_t)(by + row) * 1024 + bx + tx];
    }
    __syncthreads();
    #pragma unroll
    for (int j = 0; j < 16; ++j) {
      int row = j * 4 + ty;           // Wt[n][k] = W[k][n]
      Wt[(size_t)(bx + row) * 1024 + by + tx] = f2b(t[tx][row]);
    }
  }
}

// ---------------- GEMM: C = A[M][K](bf16) * Bt[N][K]^T + bias ----------------
// BM x 128 tile, BK=64, 4 waves, m97 2-barrier structure, global_load_lds
// staging (linear dest, pre-swizzled source; rule #21). BM=64 everywhere
// (QKV 1536 blocks = 6/CU, final 512 = 2/CU; occupancy lever validated
// R15/R17). Staging via running pointers (R19).
struct GemmB { const u16* A[3]; const u16* Bt[3]; const float* bias[3]; void* C[3]; int mode[3]; int cpx; int zshift; };

template<int BM>
__global__ __launch_bounds__(256) void gemm_bt(GemmB g) {
  constexpr int K = 1024, N = 1024;
  constexpr int MF = BM / 32;           // 16-row A-fragments per wave
  __shared__ u16 As[BM * 64];
  __shared__ u16 Bs[128 * 64];
  const int bid = blockIdx.x;
  const int lg = (bid & 7) * g.cpx + (bid >> 3);
  const int z = lg >> g.zshift;
  const int rem = lg & ((1 << g.zshift) - 1);
  const int row0 = (rem >> 3) * BM, col0 = (rem & 7) * 128;
  const u16*   Ap   = g.A[z];
  const u16*   Bt   = g.Bt[z];
  const float* bias = g.bias[z];
  const int mode = g.mode[z];
  const int tid = threadIdx.x;
  const int wid = tid >> 6, lane = tid & 63;
  const int wr = wid >> 1, wc = wid & 1;
  const int lo = lane & 15, hi = lane >> 4;
  const int rs = tid >> 3, us = tid & 7;
  const int sw = (us ^ (rs & 7)) * 8;   // pre-swizzled source column unit

  // running staging pointers (advance +64/iter)
  const u16* aG[MF];
  const u16* bG[4];
  #pragma unroll
  for (int c = 0; c < MF; ++c) aG[c] = Ap + (size_t)(row0 + c * 32 + rs) * K + sw;
  #pragma unroll
  for (int c = 0; c < 4; ++c)  bG[c] = Bt + (size_t)(col0 + c * 32 + rs) * K + sw;

  f32x4 acc[MF][4];
  const f32x4 z4 = {0.f, 0.f, 0.f, 0.f};
  #pragma unroll
  for (int i = 0; i < MF; ++i)
    #pragma unroll
    for (int j = 0; j < 4; ++j) acc[i][j] = z4;

  for (int kt = 0; kt < K / 64; ++kt) {
    __syncthreads();
    #pragma unroll
    for (int c = 0; c < MF; ++c) {
      GLOAD_LDS16(aG[c], &As[(c * 32 + rs) * 64 + us * 8]);
      aG[c] += 64;
    }
    #pragma unroll
    for (int c = 0; c < 4; ++c) {
      GLOAD_LDS16(bG[c], &Bs[(c * 32 + rs) * 64 + us * 8]);
      bG[c] += 64;
    }
    __syncthreads();   // compiler drains vmcnt before s_barrier
    #pragma unroll
    for (int ks = 0; ks < 2; ++ks) {
      bf16x8 af[MF], bfr[4];
      #pragma unroll
      for (int mf = 0; mf < MF; ++mf) {
        int r = wr * (BM / 2) + mf * 16 + lo;
        af[mf] = *(const bf16x8*)&As[r * 64 + (((ks * 4 + hi) ^ (r & 7)) << 3)];
      }
      #pragma unroll
      for (int nf = 0; nf < 4; ++nf) {
        int r = wc * 64 + nf * 16 + lo;
        bfr[nf] = *(const bf16x8*)&Bs[r * 64 + (((ks * 4 + hi) ^ (r & 7)) << 3)];
      }
      #pragma unroll
      for (int mf = 0; mf < MF; ++mf)
        #pragma unroll
        for (int nf = 0; nf < 4; ++nf)
          acc[mf][nf] = __builtin_amdgcn_mfma_f32_16x16x32_bf16(af[mf], bfr[nf], acc[mf][nf], 0, 0, 0);
    }
  }

  #pragma unroll
  for (int nf = 0; nf < 4; ++nf) {
    int col = col0 + wc * 64 + nf * 16 + lo;
    float bv = bias[col];
    #pragma unroll
    for (int mf = 0; mf < MF; ++mf) {
      int rb = row0 + wr * (BM / 2) + mf * 16 + hi * 4;   // C/D: row=(l>>4)*4+e, col=l&15
      if (mode == 2) {
        U16Q q4;
        #pragma unroll
        for (int e = 0; e < 4; ++e) q4.u[e] = f2b(acc[mf][nf][e] + bv);
        *(uint2*)&((u16*)g.C[z])[(size_t)col * 4096 + rb] = q4.d2;   // C^T[N][4096]
      } else {
        #pragma unroll
        for (int e = 0; e < 4; ++e) {
          float v = acc[mf][nf][e] + bv;
          if (mode == 1) ((float*)g.C[z])[(size_t)(rb + e) * N + col] = v;
          else           ((u16*)g.C[z])[(size_t)(rb + e) * N + col] = f2b(v);
        }
      }
    }
  }
}

// ---------------- flash attention ----------------
// BEST MEASURED (R19, 65.6us): dbuf K/V via global_load_lds, ONE barrier/iter,
// defer-max THR=8 with per-lane vote, PK4 pack, l-via-MFMA (ones-trick),
// running staging pointers. KBLK=64 (KBLK=128 regressed: occupancy+conflicts).
__global__ __launch_bounds__(256) void attn_fwd(const u16* __restrict__ Q,
                                                const u16* __restrict__ Kp,
                                                const u16* __restrict__ VpT,
                                                u16* __restrict__ O) {
  __shared__ u16 Ks[2][64 * 64];    // K tiles [kk][d], XOR-swizzled rows
  __shared__ u16 Vts[2][64 * 64];   // V^T tiles [d][kk], XOR-swizzled rows
  __shared__ u16 Ps[64 * 64];       // P tile [q][kk], per-wave rows
  const int tid = threadIdx.x;
  const int bid = blockIdx.x;       // XCD decode: xcd=bid&7 owns 4 (h,b) pairs
  const int t = bid >> 3;
  const int hb = (bid & 7) * 4 + (t >> 5);
  const int qb = t & 31;
  const int h = hb & 15, b = hb >> 4;
  const int wid = tid >> 6, lane = tid & 63;
  const int lo = lane & 15, hi = lane >> 4;
  const int rs = tid >> 3, us = tid & 7;
  const int hoff = h * 64;
  const size_t rowQ0 = (size_t)b * 2048 + (size_t)qb * 64;
  const float QSCALE = 0.125f * 1.4426950408889634f;

  // constant all-ones B operand for the l-sum MFMA
  bf16x8 vones;
  {
    U16B t1;
    #pragma unroll
    for (int j = 0; j < 8; ++j) t1.u[j] = 0x3F80u;   // bf16 1.0
    vones = t1.b8;
  }

  // Q fragments (B-operand): lane holds Q[q = wid*16+lo][d = ks*32 + hi*8 .. +8]
  bf16x8 qf[2];
  #pragma unroll
  for (int ks = 0; ks < 2; ++ks) {
    size_t r = rowQ0 + wid * 16 + lo;
    U16B in; in.i4 = *(const int4*)&Q[r * 1024 + hoff + ks * 32 + hi * 8];
    U16B o;
    #pragma unroll
    for (int j = 0; j < 8; ++j) o.u[j] = f2b(b2f(in.u[j]) * QSCALE);
    qf[ks] = o.b8;
  }

  f32x4 oacc[4];
  f32x4 lacc;                       // l in C/D layout: lacc[e] = l[q=hi*4+e]
  const f32x4 z4 = {0.f, 0.f, 0.f, 0.f};
  #pragma unroll
  for (int df = 0; df < 4; ++df) oacc[df] = z4;
  lacc = z4;
  float m_r = -1e30f;               // running max for q=wid*16+lo (replicated over hi)

  // running staging pointers (swu identical for both row-chunks: (c*32+rs)&7 == rs&7)
  const int swu = (us ^ (rs & 7)) * 8;
  const u16* kGa = Kp + ((size_t)b * 2048 + rs) * 1024 + hoff + swu;           // row rs
  const u16* kGb = kGa + 32 * 1024;                                            // row 32+rs
  const u16* vGa = VpT + (size_t)(hoff + rs) * 4096 + (size_t)b * 2048 + swu;  // row rs
  const u16* vGb = vGa + (size_t)32 * 4096;                                    // row 32+rs
  u16* dK0 = &Ks[0][rs * 64 + us * 8];
  u16* dK1 = &Ks[1][rs * 64 + us * 8];
  u16* dV0 = &Vts[0][rs * 64 + us * 8];
  u16* dV1 = &Vts[1][rs * 64 + us * 8];

  // prologue: stage tile 0 into buffer 0
  GLOAD_LDS16(kGa, dK0); GLOAD_LDS16(kGb, dK0 + 32 * 64);
  GLOAD_LDS16(vGa, dV0); GLOAD_LDS16(vGb, dV0 + 32 * 64);
  kGa += 64 * 1024; kGb += 64 * 1024; vGa += 64; vGb += 64;

  for (int kb = 0; kb < 32; ++kb) {
    const int cur = kb & 1;
    __syncthreads();   // vmcnt drained: buf[cur] ready; buf[cur^1] readers done
    if (kb < 31) {
      u16* dK = cur ? dK0 : dK1;
      u16* dV = cur ? dV0 : dV1;
      GLOAD_LDS16(kGa, dK); GLOAD_LDS16(kGb, dK + 32 * 64);
      GLOAD_LDS16(vGa, dV); GLOAD_LDS16(vGb, dV + 32 * 64);
      kGa += 64 * 1024; kGb += 64 * 1024; vGa += 64; vGb += 64;
    }

    // S^T = K Q^T : frag nf covers kk = nf*16 + hi*4 + e, q = wid*16+lo
    f32x4 sfr[4];
    #pragma unroll
    for (int nf = 0; nf < 4; ++nf) sfr[nf] = z4;
    #pragma unroll
    for (int ks = 0; ks < 2; ++ks) {
      #pragma unroll
      for (int nf = 0; nf < 4; ++nf) {
        int kk = nf * 16 + lo;
        bf16x8 kf = *(const bf16x8*)&Ks[cur][kk * 64 + (((ks * 4 + hi) ^ (kk & 7)) << 3)];
        sfr[nf] = __builtin_amdgcn_mfma_f32_16x16x32_bf16(kf, qf[ks], sfr[nf], 0, 0, 0);
      }
    }

    // defer-max vote on PER-LANE partial max (no shfl on the fast path)
    float pm = fmaxf(sfr[0][0], sfr[0][1]);
    pm = fmaxf(fmaxf(pm, sfr[0][2]), sfr[0][3]);
    pm = fmaxf(fmaxf(pm, sfr[1][0]), sfr[1][1]);
    pm = fmaxf(fmaxf(pm, sfr[1][2]), sfr[1][3]);
    pm = fmaxf(fmaxf(pm, sfr[2][0]), sfr[2][1]);
    pm = fmaxf(fmaxf(pm, sfr[2][2]), sfr[2][3]);
    pm = fmaxf(fmaxf(pm, sfr[3][0]), sfr[3][1]);
    pm = fmaxf(fmaxf(pm, sfr[3][2]), sfr[3][3]);
    if (!__all(pm <= m_r + 8.0f)) {   // rare: real max growth -> full reduce+rescale
      pm = fmaxf(pm, __shfl_xor(pm, 16));
      pm = fmaxf(pm, __shfl_xor(pm, 32));
      float mn = fmaxf(m_r, pm);
      float cc = __builtin_amdgcn_exp2f(m_r - mn);
      m_r = mn;
      float cce[4];
      #pragma unroll
      for (int e = 0; e < 4; ++e) cce[e] = __shfl(cc, hi * 4 + e);
      #pragma unroll
      for (int df = 0; df < 4; ++df)
        #pragma unroll
        for (int e = 0; e < 4; ++e) oacc[df][e] *= cce[e];
      #pragma unroll
      for (int e = 0; e < 4; ++e) lacc[e] *= cce[e];
    }
    // P pack (l comes from the ones-MFMA below)
    #pragma unroll
    for (int nf = 0; nf < 4; ++nf) {
      PK4 pk;
      #pragma unroll
      for (int e = 0; e < 4; ++e)
        pk.b[e] = (__bf16)__builtin_amdgcn_exp2f(sfr[nf][e] - m_r);
      *(uint2*)&Ps[(wid * 16 + lo) * 64 + ((nf * 16 + hi * 4) ^ ((lo & 7) << 3))] = pk.d2;
    }

    // O += P V ; l += P @ ones   (Ps rows per-wave exclusive: no block barrier)
    #pragma unroll
    for (int ksp = 0; ksp < 2; ++ksp) {
      bf16x8 pa = *(const bf16x8*)&Ps[(wid * 16 + lo) * 64 + ((((ksp * 4 + hi) ^ (lo & 7))) << 3)];
      bf16x8 vb[4];
      #pragma unroll
      for (int df = 0; df < 4; ++df) {
        int d = df * 16 + lo;
        vb[df] = *(const bf16x8*)&Vts[cur][d * 64 + (((ksp * 4 + hi) ^ (d & 7)) << 3)];
      }
      #pragma unroll
      for (int df = 0; df < 4; ++df)
        oacc[df] = __builtin_amdgcn_mfma_f32_16x16x32_bf16(pa, vb[df], oacc[df], 0, 0, 0);
      lacc = __builtin_amdgcn_mfma_f32_16x16x32_bf16(pa, vones, lacc, 0, 0, 0);
    }
  }

  // epilogue: lacc[e] = l[q=hi*4+e] already in output layout -> no gather
  float inve[4];
  #pragma unroll
  for (int e = 0; e < 4; ++e) inve[e] = __builtin_amdgcn_rcpf(lacc[e]);
  #pragma unroll
  for (int df = 0; df < 4; ++df)
    #pragma unroll
    for (int e = 0; e < 4; ++e) {
      size_t row = rowQ0 + wid * 16 + hi * 4 + e;
      O[row * 1024 + hoff + df * 16 + lo] = f2b(oacc[df][e] * inve[e]);
    }
}

// ---------------- launch ----------------
extern "C" void kernel_launch(void* const* d_in, const int* in_sizes, int n_in,
                              void* d_out, int out_size, void* d_ws, size_t ws_size,
                              hipStream_t stream) {
  (void)in_sizes; (void)n_in; (void)out_size;
  const size_t MB = 1024 * 1024;
  if (ws_size < 40 * MB) return;
  char* ws = (char*)d_ws;
  u16* Wqt = (u16*)(ws + 0 * MB);
  u16* Wkt = (u16*)(ws + 2 * MB);
  u16* Wvt = (u16*)(ws + 4 * MB);
  u16* Wot = (u16*)(ws + 6 * MB);
  u16* Vb  = (u16*)(ws + 8 * MB);    // bf16 value-input; later reused as Op
  u16* Qp  = (u16*)(ws + 16 * MB);
  u16* Kp  = (u16*)(ws + 24 * MB);
  u16* VpT = (u16*)(ws + 32 * MB);   // V^T [1024][4096]
  u16* Op  = (u16*)(ws + 8 * MB);    // reuse Vb space (dead after QKV GEMM)
  // bf16 query/key inputs parked in d_out (16MB; overwritten by final GEMM)
  u16* Qb = (u16*)d_out;
  u16* Kb = (u16*)d_out + (size_t)4 * MB;   // element offset: 8MB bytes

  Prep pp;
  pp.src[0] = (const float*)d_in[0]; pp.dst[0] = Qb;
  pp.src[1] = (const float*)d_in[1]; pp.dst[1] = Kb;
  pp.src[2] = (const float*)d_in[2]; pp.dst[2] = Vb;
  pp.W[0] = (const float*)d_in[3]; pp.Wt[0] = Wqt;
  pp.W[1] = (const float*)d_in[5]; pp.Wt[1] = Wkt;
  pp.W[2] = (const float*)d_in[7]; pp.Wt[2] = Wvt;
  pp.W[3] = (const float*)d_in[9]; pp.Wt[3] = Wot;
  hipLaunchKernelGGL(prep, dim3(2048, 1, 4), dim3(256), 0, stream, pp);

  GemmB gp;
  gp.A[0] = Qb; gp.Bt[0] = Wqt; gp.bias[0] = (const float*)d_in[4]; gp.C[0] = Qp;  gp.mode[0] = 0;
  gp.A[1] = Kb; gp.Bt[1] = Wkt; gp.bias[1] = (const float*)d_in[6]; gp.C[1] = Kp;  gp.mode[1] = 0;
  gp.A[2] = Vb; gp.Bt[2] = Wvt; gp.bias[2] = (const float*)d_in[8]; gp.C[2] = VpT; gp.mode[2] = 2;
  gp.cpx = 192; gp.zshift = 9;         // BM=64: 512 tiles per z, 1536 blocks = 6/CU
  hipLaunchKernelGGL((gemm_bt<64>), dim3(1536), dim3(256), 0, stream, gp);

  hipLaunchKernelGGL(attn_fwd, dim3(1024), dim3(256), 0, stream, Qp, Kp, VpT, Op);

  GemmB gf;
  gf.A[0] = Op; gf.Bt[0] = Wot; gf.bias[0] = (const float*)d_in[10]; gf.C[0] = (void*)d_out; gf.mode[0] = 1;
  gf.A[1] = nullptr; gf.A[2] = nullptr; gf.Bt[1] = nullptr; gf.Bt[2] = nullptr;
  gf.bias[1] = nullptr; gf.bias[2] = nullptr; gf.C[1] = nullptr; gf.C[2] = nullptr;
  gf.mode[1] = 0; gf.mode[2] = 0;
  gf.cpx = 64; gf.zshift = 9;          // 512 blocks = 2/CU
  hipLaunchKernelGGL((gemm_bt<64>), dim3(512), dim3(256), 0, stream, gf);
}